// Round 1
// baseline (496.694 us; speedup 1.0000x reference)
//
#include <hip/hip_runtime.h>
#include <hip/hip_bf16.h>

#define DIN 4096
#define DOUT 4096
#define NROWS 8192  // B*S = 4*2048

typedef __bf16 bf16x8 __attribute__((ext_vector_type(8)));
typedef float f32x4 __attribute__((ext_vector_type(4)));

// ---------------- block-level absmax reduce (4 waves, 256 threads) -------------
__device__ __forceinline__ float block_absmax(float m, float* red) {
  #pragma unroll
  for (int off = 32; off > 0; off >>= 1)
    m = fmaxf(m, __shfl_down(m, off));
  const int tid = threadIdx.x;
  if ((tid & 63) == 0) red[tid >> 6] = m;
  __syncthreads();
  return fmaxf(fmaxf(red[0], red[1]), fmaxf(red[2], red[3]));
}

// ---------------- kernel 1: FWHT + per-token 8-bit fake quant ------------------
__global__ __launch_bounds__(256) void fwht_quant_kernel(
    const float* __restrict__ in, __hip_bfloat16* __restrict__ qx,
    float* __restrict__ sx) {
  __shared__ float buf[DIN];
  __shared__ float red[4];
  const int tid = threadIdx.x;
  const size_t row = blockIdx.x;
  const float4* src = (const float4*)(in + row * DIN);
  float4* b4 = (float4*)buf;
  for (int i = tid; i < DIN / 4; i += 256) b4[i] = src[i];
  __syncthreads();
  // 12 butterfly stages, identical pairwise ops to the reference
  for (int h = 1; h < DIN; h <<= 1) {
    #pragma unroll
    for (int s = 0; s < 8; ++s) {
      int t = tid + s * 256;
      int i0 = ((t & ~(h - 1)) << 1) | (t & (h - 1));
      int i1 = i0 + h;
      float a = buf[i0], b = buf[i1];
      buf[i0] = a + b;
      buf[i1] = a - b;
    }
    __syncthreads();
  }
  const float inv = 0.015625f;  // 1/sqrt(4096) = 1/64 exact
  float m = 0.0f;
  for (int i = tid; i < DIN / 4; i += 256) {
    float4 v = b4[i];
    m = fmaxf(m, fmaxf(fmaxf(fabsf(v.x), fabsf(v.y)),
                       fmaxf(fabsf(v.z), fabsf(v.w))));
  }
  float mx = block_absmax(m, red) * inv;  // scaling by 2^-6 exact & monotone
  float scale = fmaxf(mx / 127.0f, 1e-8f);
  if (tid == 0) sx[row] = scale;
  __hip_bfloat16* dst = qx + row * DIN;
  for (int i = tid; i < DIN; i += 256) {
    float q = rintf((buf[i] * inv) / scale);  // rint = round-half-even = jnp.round
    q = fminf(fmaxf(q, -127.0f), 127.0f);
    dst[i] = __float2bfloat16(q);  // integers <=127 exact in bf16
  }
}

// ---------------- kernel 2: per-channel 4-bit weight fake quant ----------------
__global__ __launch_bounds__(256) void wquant_kernel(
    const float* __restrict__ w, __hip_bfloat16* __restrict__ qw,
    float* __restrict__ sw) {
  __shared__ float buf[DIN];
  __shared__ float red[4];
  const int tid = threadIdx.x;
  const size_t row = blockIdx.x;
  const float4* src = (const float4*)(w + row * DIN);
  float4* b4 = (float4*)buf;
  float m = 0.0f;
  for (int i = tid; i < DIN / 4; i += 256) {
    float4 v = src[i];
    b4[i] = v;
    m = fmaxf(m, fmaxf(fmaxf(fabsf(v.x), fabsf(v.y)),
                       fmaxf(fabsf(v.z), fabsf(v.w))));
  }
  float mx = block_absmax(m, red);  // internal __syncthreads covers buf writes
  float scale = fmaxf(mx / 7.0f, 1e-8f);
  if (tid == 0) sw[row] = scale;
  __hip_bfloat16* dst = qw + row * DIN;
  for (int i = tid; i < DIN; i += 256) {
    float q = rintf(buf[i] / scale);
    q = fminf(fmaxf(q, -7.0f), 7.0f);
    dst[i] = __float2bfloat16(q);
  }
}

// ---------------- kernel 3: bf16 MFMA GEMM (C = Qx * Qw^T), scaled epilogue ----
// 128x128 tile, BK=32, 4 waves in 2x2, each wave 64x64 out (4x4 16x16 frags).
__global__ __launch_bounds__(256) void gemm_kernel(
    const __hip_bfloat16* __restrict__ A,   // [NROWS][DIN] q_x (integer-valued)
    const __hip_bfloat16* __restrict__ Bt,  // [DOUT][DIN]  q_w (integer-valued)
    const float* __restrict__ sx, const float* __restrict__ sw,
    const float* __restrict__ bias, float* __restrict__ out) {
  __shared__ __hip_bfloat16 As[128 * 32];  // 8 KiB, row-major [128][32], 64B/row
  __shared__ __hip_bfloat16 Bs[128 * 32];
  const int tid = threadIdx.x;
  const int lane = tid & 63;
  const int wid = tid >> 6;
  const int wr = wid >> 1, wc = wid & 1;
  const int row0 = blockIdx.y * 128;  // M-tile
  const int col0 = blockIdx.x * 128;  // N-tile
  f32x4 acc[4][4] = {};

  for (int k0 = 0; k0 < DIN; k0 += 32) {
    // stage: 8 KiB per tile = 8 chunks of 1024B; each wave does 2 chunks of A+B
    #pragma unroll
    for (int c = wid; c < 8; c += 4) {
      unsigned off = c * 1024u + lane * 16u;  // linear LDS byte offset
      unsigned r = off >> 6, cb = off & 63u;  // row, byte-in-row
      const char* ga = (const char*)A + ((size_t)(row0 + r) * DIN + k0) * 2 + cb;
      const char* gb = (const char*)Bt + ((size_t)(col0 + r) * DIN + k0) * 2 + cb;
      __builtin_amdgcn_global_load_lds(
          (const __attribute__((address_space(1))) void*)ga,
          (__attribute__((address_space(3))) void*)((char*)As + c * 1024), 16, 0, 0);
      __builtin_amdgcn_global_load_lds(
          (const __attribute__((address_space(1))) void*)gb,
          (__attribute__((address_space(3))) void*)((char*)Bs + c * 1024), 16, 0, 0);
    }
    __syncthreads();  // compiler emits vmcnt(0) drain before barrier
    const int ko = (lane >> 4) << 4;  // byte offset: (lane>>4)*8 elems
    bf16x8 fa[4], fb[4];
    #pragma unroll
    for (int mm = 0; mm < 4; ++mm) {
      int r = wr * 64 + mm * 16 + (lane & 15);
      fa[mm] = *(const bf16x8*)((const char*)As + r * 64 + ko);
    }
    #pragma unroll
    for (int nn = 0; nn < 4; ++nn) {
      int r = wc * 64 + nn * 16 + (lane & 15);
      fb[nn] = *(const bf16x8*)((const char*)Bs + r * 64 + ko);
    }
    #pragma unroll
    for (int mm = 0; mm < 4; ++mm)
      #pragma unroll
      for (int nn = 0; nn < 4; ++nn)
        acc[mm][nn] =
            __builtin_amdgcn_mfma_f32_16x16x32_bf16(fa[mm], fb[nn], acc[mm][nn], 0, 0, 0);
    __syncthreads();
  }

  // epilogue: out = acc * sx[row] * sw[col] + bias[col]  (fp32, pre-final-quant)
  const int rbase = row0 + wr * 64, cbase = col0 + wc * 64;
  #pragma unroll
  for (int nn = 0; nn < 4; ++nn) {
    int gc = cbase + nn * 16 + (lane & 15);
    float swc = sw[gc], bc = bias[gc];
    #pragma unroll
    for (int mm = 0; mm < 4; ++mm) {
      int gr0 = rbase + mm * 16 + ((lane >> 4) << 2);
      #pragma unroll
      for (int j = 0; j < 4; ++j) {
        int gr = gr0 + j;
        out[(size_t)gr * DOUT + gc] = acc[mm][nn][j] * (sx[gr] * swc) + bc;
      }
    }
  }
}

// ---------------- kernel 4: per-token 8-bit fake quant of output, in place ----
__global__ __launch_bounds__(256) void rowquant_kernel(float* __restrict__ out) {
  __shared__ float buf[DOUT];
  __shared__ float red[4];
  const int tid = threadIdx.x;
  const size_t row = blockIdx.x;
  float4* g4 = (float4*)(out + row * DOUT);
  float4* b4 = (float4*)buf;
  float m = 0.0f;
  for (int i = tid; i < DOUT / 4; i += 256) {
    float4 v = g4[i];
    b4[i] = v;
    m = fmaxf(m, fmaxf(fmaxf(fabsf(v.x), fabsf(v.y)),
                       fmaxf(fabsf(v.z), fabsf(v.w))));
  }
  float mx = block_absmax(m, red);
  float scale = fmaxf(mx / 127.0f, 1e-8f);
  for (int i = tid; i < DOUT / 4; i += 256) {
    float4 v = b4[i];
    v.x = fminf(fmaxf(rintf(v.x / scale), -127.0f), 127.0f) * scale;
    v.y = fminf(fmaxf(rintf(v.y / scale), -127.0f), 127.0f) * scale;
    v.z = fminf(fmaxf(rintf(v.z / scale), -127.0f), 127.0f) * scale;
    v.w = fminf(fmaxf(rintf(v.w / scale), -127.0f), 127.0f) * scale;
    g4[i] = v;
  }
}

extern "C" void kernel_launch(void* const* d_in, const int* in_sizes, int n_in,
                              void* d_out, int out_size, void* d_ws, size_t ws_size,
                              hipStream_t stream) {
  (void)in_sizes; (void)n_in; (void)out_size; (void)ws_size;
  const float* input = (const float*)d_in[0];
  const float* weight = (const float*)d_in[1];
  const float* bias = (const float*)d_in[2];
  float* out = (float*)d_out;
  char* ws = (char*)d_ws;
  // workspace layout: qx 64MiB | qw 32MiB | sx 32KiB | sw 16KiB
  __hip_bfloat16* qx = (__hip_bfloat16*)ws;
  __hip_bfloat16* qw = (__hip_bfloat16*)(ws + ((size_t)64 << 20));
  float* sx = (float*)(ws + ((size_t)96 << 20));
  float* sw = (float*)(ws + ((size_t)96 << 20) + ((size_t)32 << 10));

  fwht_quant_kernel<<<NROWS, 256, 0, stream>>>(input, qx, sx);
  wquant_kernel<<<DOUT, 256, 0, stream>>>(weight, qw, sw);
  gemm_kernel<<<dim3(DOUT / 128, NROWS / 128), 256, 0, stream>>>(qx, qw, sx, sw,
                                                                 bias, out);
  rowquant_kernel<<<NROWS, 256, 0, stream>>>(out);
}

// Round 2
// 320.269 us; speedup vs baseline: 1.5509x; 1.5509x over previous
//
#include <hip/hip_runtime.h>
#include <hip/hip_bf16.h>

#define DIN 4096
#define DOUT 4096
#define NROWS 8192  // B*S = 4*2048

typedef int i32x4 __attribute__((ext_vector_type(4)));

// ---------------- block-level absmax reduce (4 waves, 256 threads) -------------
__device__ __forceinline__ float block_absmax(float m, float* red) {
  #pragma unroll
  for (int off = 32; off > 0; off >>= 1)
    m = fmaxf(m, __shfl_down(m, off));
  const int tid = threadIdx.x;
  if ((tid & 63) == 0) red[tid >> 6] = m;
  __syncthreads();
  return fmaxf(fmaxf(red[0], red[1]), fmaxf(red[2], red[3]));
}

// ---------------- kernel 1: FWHT + per-token 8-bit quant -> int8 ---------------
__global__ __launch_bounds__(256) void fwht_quant_kernel(
    const float* __restrict__ in, char* __restrict__ qx,
    float* __restrict__ sx) {
  __shared__ float buf[DIN];
  __shared__ float red[4];
  const int tid = threadIdx.x;
  const size_t row = blockIdx.x;
  const float4* src = (const float4*)(in + row * DIN);
  float4* b4 = (float4*)buf;
  for (int i = tid; i < DIN / 4; i += 256) b4[i] = src[i];
  __syncthreads();
  // 12 butterfly stages, identical pairwise ops to the reference
  for (int h = 1; h < DIN; h <<= 1) {
    #pragma unroll
    for (int s = 0; s < 8; ++s) {
      int t = tid + s * 256;
      int i0 = ((t & ~(h - 1)) << 1) | (t & (h - 1));
      int i1 = i0 + h;
      float a = buf[i0], b = buf[i1];
      buf[i0] = a + b;
      buf[i1] = a - b;
    }
    __syncthreads();
  }
  const float inv = 0.015625f;  // 1/sqrt(4096) = 1/64 exact
  float m = 0.0f;
  for (int i = tid; i < DIN / 4; i += 256) {
    float4 v = b4[i];
    m = fmaxf(m, fmaxf(fmaxf(fabsf(v.x), fabsf(v.y)),
                       fmaxf(fabsf(v.z), fabsf(v.w))));
  }
  float mx = block_absmax(m, red) * inv;  // scaling by 2^-6 exact & monotone
  float scale = fmaxf(mx / 127.0f, 1e-8f);
  if (tid == 0) sx[row] = scale;
  char* dst = qx + row * DIN;
  const float rs = 1.0f / scale;
  for (int i0 = tid * 4; i0 < DIN; i0 += 1024) {
    char4 pk;
    float q0 = fminf(fmaxf(rintf((buf[i0 + 0] * inv) * rs), -127.f), 127.f);
    float q1 = fminf(fmaxf(rintf((buf[i0 + 1] * inv) * rs), -127.f), 127.f);
    float q2 = fminf(fmaxf(rintf((buf[i0 + 2] * inv) * rs), -127.f), 127.f);
    float q3 = fminf(fmaxf(rintf((buf[i0 + 3] * inv) * rs), -127.f), 127.f);
    pk.x = (char)q0; pk.y = (char)q1; pk.z = (char)q2; pk.w = (char)q3;
    *(char4*)(dst + i0) = pk;
  }
}

// ---------------- kernel 2: per-channel 4-bit weight quant -> int8 -------------
__global__ __launch_bounds__(256) void wquant_kernel(
    const float* __restrict__ w, char* __restrict__ qw,
    float* __restrict__ sw) {
  __shared__ float buf[DIN];
  __shared__ float red[4];
  const int tid = threadIdx.x;
  const size_t row = blockIdx.x;
  const float4* src = (const float4*)(w + row * DIN);
  float4* b4 = (float4*)buf;
  float m = 0.0f;
  for (int i = tid; i < DIN / 4; i += 256) {
    float4 v = src[i];
    b4[i] = v;
    m = fmaxf(m, fmaxf(fmaxf(fabsf(v.x), fabsf(v.y)),
                       fmaxf(fabsf(v.z), fabsf(v.w))));
  }
  float mx = block_absmax(m, red);  // internal __syncthreads covers buf writes
  float scale = fmaxf(mx / 7.0f, 1e-8f);
  if (tid == 0) sw[row] = scale;
  char* dst = qw + row * DIN;
  const float rs = 1.0f / scale;
  for (int i0 = tid * 4; i0 < DIN; i0 += 1024) {
    char4 pk;
    float q0 = fminf(fmaxf(rintf(buf[i0 + 0] * rs), -7.f), 7.f);
    float q1 = fminf(fmaxf(rintf(buf[i0 + 1] * rs), -7.f), 7.f);
    float q2 = fminf(fmaxf(rintf(buf[i0 + 2] * rs), -7.f), 7.f);
    float q3 = fminf(fmaxf(rintf(buf[i0 + 3] * rs), -7.f), 7.f);
    pk.x = (char)q0; pk.y = (char)q1; pk.z = (char)q2; pk.w = (char)q3;
    *(char4*)(dst + i0) = pk;
  }
}

// ---------------- kernel 3: i8 MFMA GEMM (C = Qx * Qw^T), scaled epilogue ------
// 128x128 tile, BK=64 (64 bytes/row), 4 waves 2x2, each wave 64x64 out.
// LDS XOR swizzle: slot ^= ((row>>1)&3)<<4, applied on BOTH the global staging
// source address and the ds_read address (LDS dest stays linear per m104).
__global__ __launch_bounds__(256) void gemm_kernel(
    const char* __restrict__ A,   // [NROWS][DIN] q_x int8
    const char* __restrict__ Bt,  // [DOUT][DIN]  q_w int8
    const float* __restrict__ sx, const float* __restrict__ sw,
    const float* __restrict__ bias, float* __restrict__ out) {
  __shared__ char As[128 * 64];  // 8 KiB, row-major [128][64B]
  __shared__ char Bs[128 * 64];
  const int tid = threadIdx.x;
  const int lane = tid & 63;
  const int wid = tid >> 6;
  const int wr = wid >> 1, wc = wid & 1;
  const int row0 = blockIdx.y * 128;  // M-tile
  const int col0 = blockIdx.x * 128;  // N-tile
  i32x4 acc[4][4] = {};

  for (int k0 = 0; k0 < DIN; k0 += 64) {
    // stage 8 KiB per tile = 8 chunks of 1 KiB; each wave does 2 chunks of A+B
    #pragma unroll
    for (int c = wid; c < 8; c += 4) {
      unsigned off = c * 1024u + lane * 16u;       // linear LDS byte offset
      unsigned r = off >> 6, cb = off & 63u;       // row, byte-in-row
      unsigned cbl = cb ^ (((r >> 1) & 3u) << 4);  // inverse-swizzled source slot
      const char* ga = A + (size_t)(row0 + r) * DIN + k0 + cbl;
      const char* gb = Bt + (size_t)(col0 + r) * DIN + k0 + cbl;
      __builtin_amdgcn_global_load_lds(
          (const __attribute__((address_space(1))) void*)ga,
          (__attribute__((address_space(3))) void*)(As + c * 1024), 16, 0, 0);
      __builtin_amdgcn_global_load_lds(
          (const __attribute__((address_space(1))) void*)gb,
          (__attribute__((address_space(3))) void*)(Bs + c * 1024), 16, 0, 0);
    }
    __syncthreads();
    const int ko = (lane >> 4) << 4;  // 16-byte k-slot per 16-lane group
    i32x4 fa[4], fb[4];
    #pragma unroll
    for (int mm = 0; mm < 4; ++mm) {
      int r = wr * 64 + mm * 16 + (lane & 15);
      int sl = ko ^ (((r >> 1) & 3) << 4);  // swizzled read slot
      fa[mm] = *(const i32x4*)(As + r * 64 + sl);
    }
    #pragma unroll
    for (int nn = 0; nn < 4; ++nn) {
      int r = wc * 64 + nn * 16 + (lane & 15);
      int sl = ko ^ (((r >> 1) & 3) << 4);
      fb[nn] = *(const i32x4*)(Bs + r * 64 + sl);
    }
    #pragma unroll
    for (int mm = 0; mm < 4; ++mm)
      #pragma unroll
      for (int nn = 0; nn < 4; ++nn)
        acc[mm][nn] =
            __builtin_amdgcn_mfma_i32_16x16x64_i8(fa[mm], fb[nn], acc[mm][nn], 0, 0, 0);
    __syncthreads();
  }

  // epilogue: out = (float)acc * sx[row] * sw[col] + bias[col]  (exact i32)
  const int rbase = row0 + wr * 64, cbase = col0 + wc * 64;
  #pragma unroll
  for (int nn = 0; nn < 4; ++nn) {
    int gc = cbase + nn * 16 + (lane & 15);
    float swc = sw[gc], bc = bias[gc];
    #pragma unroll
    for (int mm = 0; mm < 4; ++mm) {
      int gr0 = rbase + mm * 16 + ((lane >> 4) << 2);
      #pragma unroll
      for (int j = 0; j < 4; ++j) {
        int gr = gr0 + j;
        out[(size_t)gr * DOUT + gc] =
            (float)acc[mm][nn][j] * (sx[gr] * swc) + bc;
      }
    }
  }
}

// ---------------- kernel 4: per-token 8-bit fake quant of output, in place ----
__global__ __launch_bounds__(256) void rowquant_kernel(float* __restrict__ out) {
  __shared__ float buf[DOUT];
  __shared__ float red[4];
  const int tid = threadIdx.x;
  const size_t row = blockIdx.x;
  float4* g4 = (float4*)(out + row * DOUT);
  float4* b4 = (float4*)buf;
  float m = 0.0f;
  for (int i = tid; i < DOUT / 4; i += 256) {
    float4 v = g4[i];
    b4[i] = v;
    m = fmaxf(m, fmaxf(fmaxf(fabsf(v.x), fabsf(v.y)),
                       fmaxf(fabsf(v.z), fabsf(v.w))));
  }
  float mx = block_absmax(m, red);
  float scale = fmaxf(mx / 127.0f, 1e-8f);
  for (int i = tid; i < DOUT / 4; i += 256) {
    float4 v = b4[i];
    v.x = fminf(fmaxf(rintf(v.x / scale), -127.0f), 127.0f) * scale;
    v.y = fminf(fmaxf(rintf(v.y / scale), -127.0f), 127.0f) * scale;
    v.z = fminf(fmaxf(rintf(v.z / scale), -127.0f), 127.0f) * scale;
    v.w = fminf(fmaxf(rintf(v.w / scale), -127.0f), 127.0f) * scale;
    g4[i] = v;
  }
}

extern "C" void kernel_launch(void* const* d_in, const int* in_sizes, int n_in,
                              void* d_out, int out_size, void* d_ws, size_t ws_size,
                              hipStream_t stream) {
  (void)in_sizes; (void)n_in; (void)out_size; (void)ws_size;
  const float* input = (const float*)d_in[0];
  const float* weight = (const float*)d_in[1];
  const float* bias = (const float*)d_in[2];
  float* out = (float*)d_out;
  char* ws = (char*)d_ws;
  // workspace layout: qx 32MiB | qw 16MiB | sx 32KiB | sw 16KiB
  char* qx = ws;
  char* qw = ws + ((size_t)32 << 20);
  float* sx = (float*)(ws + ((size_t)48 << 20));
  float* sw = (float*)(ws + ((size_t)48 << 20) + ((size_t)32 << 10));

  fwht_quant_kernel<<<NROWS, 256, 0, stream>>>(input, qx, sx);
  wquant_kernel<<<DOUT, 256, 0, stream>>>(weight, qw, sw);
  gemm_kernel<<<dim3(DOUT / 128, NROWS / 128), 256, 0, stream>>>(qx, qw, sx, sw,
                                                                 bias, out);
  rowquant_kernel<<<NROWS, 256, 0, stream>>>(out);
}

// Round 3
// 264.599 us; speedup vs baseline: 1.8772x; 1.2104x over previous
//
#include <hip/hip_runtime.h>
#include <hip/hip_bf16.h>

#define DIN 4096
#define DOUT 4096
#define NROWS 8192  // B*S = 4*2048

typedef int i32x4 __attribute__((ext_vector_type(4)));

// ---------------- block-level absmax reduce (4 waves, 256 threads) -------------
__device__ __forceinline__ float block_absmax(float m, float* red) {
  #pragma unroll
  for (int off = 32; off > 0; off >>= 1)
    m = fmaxf(m, __shfl_down(m, off));
  const int tid = threadIdx.x;
  if ((tid & 63) == 0) red[tid >> 6] = m;
  __syncthreads();
  return fmaxf(fmaxf(red[0], red[1]), fmaxf(red[2], red[3]));
}

// ---------------- kernel 1: FWHT + per-token 8-bit quant -> int8 ---------------
__global__ __launch_bounds__(256) void fwht_quant_kernel(
    const float* __restrict__ in, char* __restrict__ qx,
    float* __restrict__ sx) {
  __shared__ float buf[DIN];
  __shared__ float red[4];
  const int tid = threadIdx.x;
  const size_t row = blockIdx.x;
  const float4* src = (const float4*)(in + row * DIN);
  float4* b4 = (float4*)buf;
  for (int i = tid; i < DIN / 4; i += 256) b4[i] = src[i];
  __syncthreads();
  for (int h = 1; h < DIN; h <<= 1) {
    #pragma unroll
    for (int s = 0; s < 8; ++s) {
      int t = tid + s * 256;
      int i0 = ((t & ~(h - 1)) << 1) | (t & (h - 1));
      int i1 = i0 + h;
      float a = buf[i0], b = buf[i1];
      buf[i0] = a + b;
      buf[i1] = a - b;
    }
    __syncthreads();
  }
  const float inv = 0.015625f;  // 1/sqrt(4096) exact
  float m = 0.0f;
  for (int i = tid; i < DIN / 4; i += 256) {
    float4 v = b4[i];
    m = fmaxf(m, fmaxf(fmaxf(fabsf(v.x), fabsf(v.y)),
                       fmaxf(fabsf(v.z), fabsf(v.w))));
  }
  float mx = block_absmax(m, red) * inv;
  float scale = fmaxf(mx / 127.0f, 1e-8f);
  if (tid == 0) sx[row] = scale;
  char* dst = qx + row * DIN;
  const float rs = 1.0f / scale;
  for (int i0 = tid * 4; i0 < DIN; i0 += 1024) {
    char4 pk;
    float q0 = fminf(fmaxf(rintf((buf[i0 + 0] * inv) * rs), -127.f), 127.f);
    float q1 = fminf(fmaxf(rintf((buf[i0 + 1] * inv) * rs), -127.f), 127.f);
    float q2 = fminf(fmaxf(rintf((buf[i0 + 2] * inv) * rs), -127.f), 127.f);
    float q3 = fminf(fmaxf(rintf((buf[i0 + 3] * inv) * rs), -127.f), 127.f);
    pk.x = (char)q0; pk.y = (char)q1; pk.z = (char)q2; pk.w = (char)q3;
    *(char4*)(dst + i0) = pk;
  }
}

// ---------------- kernel 2: per-channel 4-bit weight quant -> int8 -------------
__global__ __launch_bounds__(256) void wquant_kernel(
    const float* __restrict__ w, char* __restrict__ qw,
    float* __restrict__ sw) {
  __shared__ float buf[DIN];
  __shared__ float red[4];
  const int tid = threadIdx.x;
  const size_t row = blockIdx.x;
  const float4* src = (const float4*)(w + row * DIN);
  float4* b4 = (float4*)buf;
  float m = 0.0f;
  for (int i = tid; i < DIN / 4; i += 256) {
    float4 v = src[i];
    b4[i] = v;
    m = fmaxf(m, fmaxf(fmaxf(fabsf(v.x), fabsf(v.y)),
                       fmaxf(fabsf(v.z), fabsf(v.w))));
  }
  float mx = block_absmax(m, red);
  float scale = fmaxf(mx / 7.0f, 1e-8f);
  if (tid == 0) sw[row] = scale;
  char* dst = qw + row * DIN;
  const float rs = 1.0f / scale;
  for (int i0 = tid * 4; i0 < DIN; i0 += 1024) {
    char4 pk;
    float q0 = fminf(fmaxf(rintf(buf[i0 + 0] * rs), -7.f), 7.f);
    float q1 = fminf(fmaxf(rintf(buf[i0 + 1] * rs), -7.f), 7.f);
    float q2 = fminf(fmaxf(rintf(buf[i0 + 2] * rs), -7.f), 7.f);
    float q3 = fminf(fmaxf(rintf(buf[i0 + 3] * rs), -7.f), 7.f);
    pk.x = (char)q0; pk.y = (char)q1; pk.z = (char)q2; pk.w = (char)q3;
    *(char4*)(dst + i0) = pk;
  }
}

// ---------------- kernel 3: i8 MFMA GEMM, 256x256 tile, 8-phase schedule -------
// 8 waves (512 thr). K-tile = 128 int8 (128 B/row). 2 K-tiles per iteration.
// LDS 128 KiB: As[2][256][128] @ 0, Bs[2][256][128] @ 65536.
// Phase q computes C-row-slab [64q,64q+64); waves 2x4 within slab
// (wr: 32-row half, wc: 64-col quarter). B-frags read once per K-tile (ph1/ph5).
// Swizzle: 16B-slot ^= (row&7); applied on pre-swizzled global src (linear LDS
// dest for global_load_lds) and on the ds_read address. vmcnt(6) at ph4/ph8.
__global__ __launch_bounds__(512, 2) void gemm_kernel(
    const char* __restrict__ A,   // [NROWS][DIN] q_x int8
    const char* __restrict__ Bt,  // [DOUT][DIN]  q_w int8
    const float* __restrict__ sx, const float* __restrict__ sw,
    const float* __restrict__ bias, float* __restrict__ out) {
  __shared__ char lds[131072];
  const int tid = threadIdx.x;
  const int lane = tid & 63;
  const int wid = tid >> 6;
  const int wr = wid >> 2;  // 0..1
  const int wc = wid & 3;   // 0..3
  int bid = blockIdx.x;                    // 512 blocks
  int swz = (bid & 7) * 64 + (bid >> 3);   // bijective XCD swizzle (512%8==0)
  const int tm = swz >> 4;                 // 0..31
  const int tn = swz & 15;                 // 0..15
  const size_t row0 = (size_t)tm * 256;
  const size_t col0 = (size_t)tn * 256;
  const int slot0 = (((lane >> 4) ^ (lane & 7)) << 4);  // swizzled 16B slot

  i32x4 acc[4][2][4] = {};  // [slab q][mm][nn]
  i32x4 fb[4][2];           // [nn][kk] — persists across a 4-phase group
  i32x4 fa[2][2];           // [mm][kk] — per phase

#define STAGE(MAT, GROW0, KT, LBASE)                                          \
  {                                                                           \
    _Pragma("unroll")                                                         \
    for (int j = 0; j < 2; ++j) {                                             \
      int chunk = j * 8 + wid;                                                \
      int rr = chunk * 8 + (lane >> 3);                                       \
      int cc = (KT) * 128 + (((lane & 7) ^ (lane >> 3)) << 4);                \
      const char* src = (MAT) + ((GROW0) + rr) * (size_t)DIN + cc;            \
      __builtin_amdgcn_global_load_lds(                                       \
          (const __attribute__((address_space(1))) void*)src,                 \
          (__attribute__((address_space(3))) void*)(lds + (LBASE) +           \
                                                    chunk * 1024),            \
          16, 0, 0);                                                          \
    }                                                                         \
  }
#define STAGE_A(P, HALF, KT) \
  STAGE(A, row0 + (HALF) * 128, KT, (P) * 32768 + (HALF) * 16384)
#define STAGE_B(P, HALF, KT) \
  STAGE(Bt, col0 + (HALF) * 128, KT, 65536 + (P) * 32768 + (HALF) * 16384)

#define DS_A(Q, P)                                                            \
  {                                                                           \
    _Pragma("unroll")                                                         \
    for (int mm = 0; mm < 2; ++mm) {                                          \
      int ar = (Q) * 64 + wr * 32 + mm * 16 + (lane & 15);                    \
      _Pragma("unroll")                                                       \
      for (int kk = 0; kk < 2; ++kk)                                          \
        fa[mm][kk] =                                                          \
            *(const i32x4*)(lds + (P) * 32768 + ar * 128 + (slot0 ^ (kk * 64))); \
    }                                                                         \
  }
#define DS_B(P)                                                               \
  {                                                                           \
    _Pragma("unroll")                                                         \
    for (int nn = 0; nn < 4; ++nn) {                                          \
      int br = wc * 64 + nn * 16 + (lane & 15);                               \
      _Pragma("unroll")                                                       \
      for (int kk = 0; kk < 2; ++kk)                                          \
        fb[nn][kk] = *(const i32x4*)(lds + 65536 + (P) * 32768 + br * 128 +   \
                                     (slot0 ^ (kk * 64)));                    \
    }                                                                         \
  }
#define MFMA16(Q)                                                             \
  {                                                                           \
    __builtin_amdgcn_s_setprio(1);                                            \
    _Pragma("unroll")                                                         \
    for (int kk = 0; kk < 2; ++kk)                                            \
      _Pragma("unroll")                                                       \
      for (int mm = 0; mm < 2; ++mm)                                          \
        _Pragma("unroll")                                                     \
        for (int nn = 0; nn < 4; ++nn)                                        \
          acc[Q][mm][nn] = __builtin_amdgcn_mfma_i32_16x16x64_i8(             \
              fa[mm][kk], fb[nn][kk], acc[Q][mm][nn], 0, 0, 0);               \
    __builtin_amdgcn_s_setprio(0);                                            \
  }
#define BAR() __builtin_amdgcn_s_barrier()
#define WAIT_LGKM0() asm volatile("s_waitcnt lgkmcnt(0)" ::: "memory")

  // -------- prologue: kt0 -> buf0 (4 half-tiles), kt1 -> buf1 (3 half-tiles)
  STAGE_B(0, 0, 0); STAGE_B(0, 1, 0); STAGE_A(0, 0, 0); STAGE_A(0, 1, 0);
  STAGE_B(1, 0, 1); STAGE_B(1, 1, 1); STAGE_A(1, 0, 1);
  asm volatile("s_waitcnt vmcnt(6)" ::: "memory");  // buf0 fully landed
  BAR();

  #pragma unroll 1
  for (int i = 0; i < 16; ++i) {
    const int a = 2 * i, b = 2 * i + 1;
    const bool nl = (i < 15);
    // ---- ph1: slab0 of buf0; stage buf1.A-h1 <- kt b (completes buf1)
    DS_A(0, 0); DS_B(0);
    STAGE_A(1, 1, b);
    asm volatile("s_waitcnt lgkmcnt(8)" ::: "memory");
    BAR(); WAIT_LGKM0();
    MFMA16(0);
    BAR();
    // ---- ph2: slab1 of buf0; stage buf0.B-h0 <- kt a+2
    DS_A(1, 0);
    if (nl) STAGE_B(0, 0, a + 2);
    BAR(); WAIT_LGKM0();
    MFMA16(1);
    BAR();
    // ---- ph3: slab2; stage buf0.B-h1
    DS_A(2, 0);
    if (nl) STAGE_B(0, 1, a + 2);
    BAR(); WAIT_LGKM0();
    MFMA16(2);
    BAR();
    // ---- ph4: slab3; stage buf0.A-h0; vmcnt -> buf1 ready
    DS_A(3, 0);
    if (nl) STAGE_A(0, 0, a + 2);
    BAR(); WAIT_LGKM0();
    MFMA16(3);
    if (nl) { asm volatile("s_waitcnt vmcnt(6)" ::: "memory"); }
    else    { asm volatile("s_waitcnt vmcnt(0)" ::: "memory"); }
    BAR();
    // ---- ph5: slab0 of buf1; stage buf0.A-h1
    DS_A(0, 1); DS_B(1);
    if (nl) STAGE_A(0, 1, a + 2);
    asm volatile("s_waitcnt lgkmcnt(8)" ::: "memory");
    BAR(); WAIT_LGKM0();
    MFMA16(0);
    BAR();
    // ---- ph6: slab1 of buf1; stage buf1.B-h0 <- kt b+2
    DS_A(1, 1);
    if (nl) STAGE_B(1, 0, b + 2);
    BAR(); WAIT_LGKM0();
    MFMA16(1);
    BAR();
    // ---- ph7: slab2; stage buf1.B-h1
    DS_A(2, 1);
    if (nl) STAGE_B(1, 1, b + 2);
    BAR(); WAIT_LGKM0();
    MFMA16(2);
    BAR();
    // ---- ph8: slab3; stage buf1.A-h0; vmcnt -> buf0 ready for next iter
    DS_A(3, 1);
    if (nl) STAGE_A(1, 0, b + 2);
    BAR(); WAIT_LGKM0();
    MFMA16(3);
    if (nl) { asm volatile("s_waitcnt vmcnt(6)" ::: "memory"); }
    BAR();
  }

  // -------- epilogue: out = acc * sx[row]*sw[col] + bias[col]
  float swv[4], bv[4];
  #pragma unroll
  for (int nn = 0; nn < 4; ++nn) {
    size_t gc = col0 + wc * 64 + nn * 16 + (lane & 15);
    swv[nn] = sw[gc];
    bv[nn] = bias[gc];
  }
  #pragma unroll
  for (int q = 0; q < 4; ++q) {
    #pragma unroll
    for (int mm = 0; mm < 2; ++mm) {
      #pragma unroll
      for (int j = 0; j < 4; ++j) {
        size_t gr = row0 + q * 64 + wr * 32 + mm * 16 + ((lane >> 4) << 2) + j;
        float sxr = sx[gr];
        float* orow = out + gr * DOUT + col0 + wc * 64 + (lane & 15);
        #pragma unroll
        for (int nn = 0; nn < 4; ++nn)
          orow[nn * 16] = (float)acc[q][mm][nn][j] * (sxr * swv[nn]) + bv[nn];
      }
    }
  }
#undef STAGE
#undef STAGE_A
#undef STAGE_B
#undef DS_A
#undef DS_B
#undef MFMA16
#undef BAR
#undef WAIT_LGKM0
}

// ---------------- kernel 4: per-token 8-bit fake quant of output, in place ----
__global__ __launch_bounds__(256) void rowquant_kernel(float* __restrict__ out) {
  __shared__ float buf[DOUT];
  __shared__ float red[4];
  const int tid = threadIdx.x;
  const size_t row = blockIdx.x;
  float4* g4 = (float4*)(out + row * DOUT);
  float4* b4 = (float4*)buf;
  float m = 0.0f;
  for (int i = tid; i < DOUT / 4; i += 256) {
    float4 v = g4[i];
    b4[i] = v;
    m = fmaxf(m, fmaxf(fmaxf(fabsf(v.x), fabsf(v.y)),
                       fmaxf(fabsf(v.z), fabsf(v.w))));
  }
  float mx = block_absmax(m, red);
  float scale = fmaxf(mx / 127.0f, 1e-8f);
  for (int i = tid; i < DOUT / 4; i += 256) {
    float4 v = b4[i];
    v.x = fminf(fmaxf(rintf(v.x / scale), -127.0f), 127.0f) * scale;
    v.y = fminf(fmaxf(rintf(v.y / scale), -127.0f), 127.0f) * scale;
    v.z = fminf(fmaxf(rintf(v.z / scale), -127.0f), 127.0f) * scale;
    v.w = fminf(fmaxf(rintf(v.w / scale), -127.0f), 127.0f) * scale;
    g4[i] = v;
  }
}

extern "C" void kernel_launch(void* const* d_in, const int* in_sizes, int n_in,
                              void* d_out, int out_size, void* d_ws, size_t ws_size,
                              hipStream_t stream) {
  (void)in_sizes; (void)n_in; (void)out_size; (void)ws_size;
  const float* input = (const float*)d_in[0];
  const float* weight = (const float*)d_in[1];
  const float* bias = (const float*)d_in[2];
  float* out = (float*)d_out;
  char* ws = (char*)d_ws;
  char* qx = ws;
  char* qw = ws + ((size_t)32 << 20);
  float* sx = (float*)(ws + ((size_t)48 << 20));
  float* sw = (float*)(ws + ((size_t)48 << 20) + ((size_t)32 << 10));

  fwht_quant_kernel<<<NROWS, 256, 0, stream>>>(input, qx, sx);
  wquant_kernel<<<DOUT, 256, 0, stream>>>(weight, qw, sw);
  gemm_kernel<<<512, 512, 0, stream>>>(qx, qw, sx, sw, bias, out);
  rowquant_kernel<<<NROWS, 256, 0, stream>>>(out);
}

// Round 4
// 225.060 us; speedup vs baseline: 2.2069x; 1.1757x over previous
//
#include <hip/hip_runtime.h>
#include <hip/hip_bf16.h>

#define DIN 4096
#define DOUT 4096
#define NROWS 8192  // B*S = 4*2048

typedef int i32x4 __attribute__((ext_vector_type(4)));

// ---------------- block-level absmax reduce (4 waves, 256 threads) -------------
__device__ __forceinline__ float block_absmax(float m, float* red) {
  #pragma unroll
  for (int off = 32; off > 0; off >>= 1)
    m = fmaxf(m, __shfl_down(m, off));
  const int tid = threadIdx.x;
  if ((tid & 63) == 0) red[tid >> 6] = m;
  __syncthreads();
  return fmaxf(fmaxf(red[0], red[1]), fmaxf(red[2], red[3]));
}

// ---------------- kernel 1: FWHT (radix-16, bit-exact order) + 8b quant --------
// 256 threads, 16 elems/thread in registers. 3 phases of 4 in-reg stages each,
// ascending h (exact reference op tree). Padded LDS map p(i)=i+(i>>4) keeps all
// exchange patterns <=2-way bank-aliased (free).
__global__ __launch_bounds__(256) void fwht_quant_kernel(
    const float* __restrict__ in, char* __restrict__ qx,
    float* __restrict__ sx) {
  __shared__ float lds[4352];  // 4096 + 256 pad
  __shared__ float red[4];
  const int tid = threadIdx.x;
  const size_t row = blockIdx.x;
  const int th = tid >> 4, tl = tid & 15;
  float v[16];

  // load 16 contiguous floats: i = tid*16 + j
  const float4* src = (const float4*)(in + row * DIN);
  #pragma unroll
  for (int k = 0; k < 4; ++k) {
    float4 f = src[tid * 4 + k];
    v[4 * k + 0] = f.x; v[4 * k + 1] = f.y;
    v[4 * k + 2] = f.z; v[4 * k + 3] = f.w;
  }
  // stages h = 1,2,4,8 (bits 0-3 of i, = bits of j)
  #pragma unroll
  for (int hb = 1; hb < 16; hb <<= 1)
    #pragma unroll
    for (int j = 0; j < 16; ++j)
      if (!(j & hb)) {
        float a0 = v[j], b0 = v[j | hb];
        v[j] = a0 + b0; v[j | hb] = a0 - b0;
      }
  // scatter (i = tid*16+j -> p = 17*tid + j, conflict-free)
  #pragma unroll
  for (int j = 0; j < 16; ++j) lds[17 * tid + j] = v[j];
  __syncthreads();
  // gather i = th*256 + j*16 + tl -> p = 272*th + 17*j + tl (2-way, free)
  #pragma unroll
  for (int j = 0; j < 16; ++j) v[j] = lds[272 * th + 17 * j + tl];
  // stages h = 16,32,64,128 (bits 4-7 of i, = bits of j)
  #pragma unroll
  for (int hb = 1; hb < 16; hb <<= 1)
    #pragma unroll
    for (int j = 0; j < 16; ++j)
      if (!(j & hb)) {
        float a0 = v[j], b0 = v[j | hb];
        v[j] = a0 + b0; v[j | hb] = a0 - b0;
      }
  // write back to the same cells (only this thread touches them), then sync
  #pragma unroll
  for (int j = 0; j < 16; ++j) lds[272 * th + 17 * j + tl] = v[j];
  __syncthreads();
  // gather i = j*256 + tid -> p = 272*j + 17*th + tl
  #pragma unroll
  for (int j = 0; j < 16; ++j) v[j] = lds[272 * j + 17 * th + tl];
  // stages h = 256,512,1024,2048 (bits 8-11 of i, = bits of j)
  #pragma unroll
  for (int hb = 1; hb < 16; hb <<= 1)
    #pragma unroll
    for (int j = 0; j < 16; ++j)
      if (!(j & hb)) {
        float a0 = v[j], b0 = v[j | hb];
        v[j] = a0 + b0; v[j | hb] = a0 - b0;
      }
  // local absmax + park values for the coalesced quant pass
  float m = 0.0f;
  #pragma unroll
  for (int j = 0; j < 16; ++j) m = fmaxf(m, fabsf(v[j]));
  #pragma unroll
  for (int j = 0; j < 16; ++j) lds[272 * j + 17 * th + tl] = v[j];
  float mx = block_absmax(m, red) * 0.015625f;  // barrier orders lds writes too
  float scale = fmaxf(mx / 127.0f, 1e-8f);
  if (tid == 0) sx[row] = scale;
  const float rs = 1.0f / scale;
  // read 16 contiguous (p = 17*tid+j), quantize, pack, 16B store
  char pk[16];
  #pragma unroll
  for (int j = 0; j < 16; ++j) {
    float q = fminf(fmaxf(rintf((lds[17 * tid + j] * 0.015625f) * rs), -127.f),
                    127.f);
    pk[j] = (char)q;
  }
  *(int4*)(qx + row * DIN + (size_t)tid * 16) = *(const int4*)pk;
}

// ---------------- kernel 2: per-channel 4-bit weight quant -> int8 -------------
__global__ __launch_bounds__(256) void wquant_kernel(
    const float* __restrict__ w, char* __restrict__ qw,
    float* __restrict__ sw) {
  __shared__ float buf[DIN];
  __shared__ float red[4];
  const int tid = threadIdx.x;
  const size_t row = blockIdx.x;
  const float4* src = (const float4*)(w + row * DIN);
  float4* b4 = (float4*)buf;
  float m = 0.0f;
  for (int i = tid; i < DIN / 4; i += 256) {
    float4 v = src[i];
    b4[i] = v;
    m = fmaxf(m, fmaxf(fmaxf(fabsf(v.x), fabsf(v.y)),
                       fmaxf(fabsf(v.z), fabsf(v.w))));
  }
  float mx = block_absmax(m, red);
  float scale = fmaxf(mx / 7.0f, 1e-8f);
  if (tid == 0) sw[row] = scale;
  char* dst = qw + row * DIN;
  const float rs = 1.0f / scale;
  for (int i0 = tid * 4; i0 < DIN; i0 += 1024) {
    char4 pk;
    float q0 = fminf(fmaxf(rintf(buf[i0 + 0] * rs), -7.f), 7.f);
    float q1 = fminf(fmaxf(rintf(buf[i0 + 1] * rs), -7.f), 7.f);
    float q2 = fminf(fmaxf(rintf(buf[i0 + 2] * rs), -7.f), 7.f);
    float q3 = fminf(fmaxf(rintf(buf[i0 + 3] * rs), -7.f), 7.f);
    pk.x = (char)q0; pk.y = (char)q1; pk.z = (char)q2; pk.w = (char)q3;
    *(char4*)(dst + i0) = pk;
  }
}

// ---------------- kernel 3: i8 MFMA GEMM, 256x256 tile, 4-phase schedule -------
// 8 waves. K-tile = 128 int8. 2 K-tiles/iter, 4 merged phases x 32 MFMA.
// Region ledger (write-after-read barrier-separated; vmcnt lands before read):
//   mph1: DS slabs0,1+B of buf0 | stage A11(b)           | buf1.Ah1 read prev mph4
//   mph2: DS slabs2,3 of buf0   | stage B00,B01,A00(a+2) | read mph1; vmcnt(6)->buf1
//   mph3: DS slabs0,1+B of buf1 | stage A01(a+2)         | buf0.Ah1 read mph2
//   mph4: DS slabs2,3 of buf1   | stage B10,B11,A10(b+2) | read mph3; vmcnt(6)->buf0
__global__ __launch_bounds__(512, 2) void gemm_kernel(
    const char* __restrict__ A,   // [NROWS][DIN] q_x int8
    const char* __restrict__ Bt,  // [DOUT][DIN]  q_w int8
    const float* __restrict__ sx, const float* __restrict__ sw,
    const float* __restrict__ bias, float* __restrict__ out) {
  __shared__ char lds[131072];
  const int tid = threadIdx.x;
  const int lane = tid & 63;
  const int wid = tid >> 6;
  const int wr = wid >> 2;  // 0..1
  const int wc = wid & 3;   // 0..3
  int bid = blockIdx.x;                    // 512 blocks
  int swz = (bid & 7) * 64 + (bid >> 3);   // bijective XCD swizzle (512%8==0)
  const int tm = swz >> 4;                 // 0..31
  const int tn = swz & 15;                 // 0..15
  const size_t row0 = (size_t)tm * 256;
  const size_t col0 = (size_t)tn * 256;
  const int slot0 = (((lane >> 4) ^ (lane & 7)) << 4);  // swizzled 16B slot

  i32x4 acc[4][2][4] = {};  // [slab q][mm][nn]
  i32x4 fb[4][2];           // [nn][kk] — persists across a 2-phase group
  i32x4 fa[2][2][2];        // [slab-in-phase][mm][kk]

#define STAGE(MAT, GROW0, KT, LBASE)                                          \
  {                                                                           \
    _Pragma("unroll")                                                         \
    for (int j = 0; j < 2; ++j) {                                             \
      int chunk = j * 8 + wid;                                                \
      int rr = chunk * 8 + (lane >> 3);                                       \
      int cc = (KT) * 128 + (((lane & 7) ^ (lane >> 3)) << 4);                \
      const char* src = (MAT) + ((GROW0) + rr) * (size_t)DIN + cc;            \
      __builtin_amdgcn_global_load_lds(                                       \
          (const __attribute__((address_space(1))) void*)src,                 \
          (__attribute__((address_space(3))) void*)(lds + (LBASE) +           \
                                                    chunk * 1024),            \
          16, 0, 0);                                                          \
    }                                                                         \
  }
#define STAGE_A(P, HALF, KT) \
  STAGE(A, row0 + (HALF) * 128, KT, (P) * 32768 + (HALF) * 16384)
#define STAGE_B(P, HALF, KT) \
  STAGE(Bt, col0 + (HALF) * 128, KT, 65536 + (P) * 32768 + (HALF) * 16384)

#define DS_A2(Q0, P)                                                          \
  {                                                                           \
    _Pragma("unroll")                                                         \
    for (int s = 0; s < 2; ++s) {                                             \
      _Pragma("unroll")                                                       \
      for (int mm = 0; mm < 2; ++mm) {                                        \
        int ar = ((Q0) + s) * 64 + wr * 32 + mm * 16 + (lane & 15);           \
        _Pragma("unroll")                                                     \
        for (int kk = 0; kk < 2; ++kk)                                        \
          fa[s][mm][kk] = *(const i32x4*)(lds + (P) * 32768 + ar * 128 +      \
                                          (slot0 ^ (kk * 64)));               \
      }                                                                       \
    }                                                                         \
  }
#define DS_B(P)                                                               \
  {                                                                           \
    _Pragma("unroll")                                                         \
    for (int nn = 0; nn < 4; ++nn) {                                          \
      int br = wc * 64 + nn * 16 + (lane & 15);                               \
      _Pragma("unroll")                                                       \
      for (int kk = 0; kk < 2; ++kk)                                          \
        fb[nn][kk] = *(const i32x4*)(lds + 65536 + (P) * 32768 + br * 128 +   \
                                     (slot0 ^ (kk * 64)));                    \
    }                                                                         \
  }
#define MFMA32(Q0)                                                            \
  {                                                                           \
    __builtin_amdgcn_s_setprio(1);                                            \
    _Pragma("unroll")                                                         \
    for (int kk = 0; kk < 2; ++kk)                                            \
      _Pragma("unroll")                                                       \
      for (int s = 0; s < 2; ++s)                                             \
        _Pragma("unroll")                                                     \
        for (int mm = 0; mm < 2; ++mm)                                        \
          _Pragma("unroll")                                                   \
          for (int nn = 0; nn < 4; ++nn)                                      \
            acc[(Q0) + s][mm][nn] = __builtin_amdgcn_mfma_i32_16x16x64_i8(    \
                fa[s][mm][kk], fb[nn][kk], acc[(Q0) + s][mm][nn], 0, 0, 0);   \
    __builtin_amdgcn_s_setprio(0);                                            \
  }
#define BAR() __builtin_amdgcn_s_barrier()
#define WAIT_LGKM0() asm volatile("s_waitcnt lgkmcnt(0)" ::: "memory")

  // -------- prologue: kt0 -> buf0 (4 half-tiles), kt1 -> buf1 (3 half-tiles)
  STAGE_B(0, 0, 0); STAGE_B(0, 1, 0); STAGE_A(0, 0, 0); STAGE_A(0, 1, 0);
  STAGE_B(1, 0, 1); STAGE_B(1, 1, 1); STAGE_A(1, 0, 1);
  asm volatile("s_waitcnt vmcnt(6)" ::: "memory");  // buf0 fully landed
  BAR();

  #pragma unroll 1
  for (int i = 0; i < 16; ++i) {
    const int a = 2 * i, b = 2 * i + 1;
    const bool nl = (i < 15);
    // ---- mph1: slabs 0,1 of buf0 (+fb buf0); stage buf1.A-h1 <- kt b
    DS_A2(0, 0); DS_B(0);
    STAGE_A(1, 1, b);
    asm volatile("s_waitcnt lgkmcnt(8)" ::: "memory");
    BAR(); WAIT_LGKM0();
    MFMA32(0);
    BAR();
    // ---- mph2: slabs 2,3 of buf0; stage buf0.{B,A-h0} <- kt a+2; buf1 ready
    DS_A2(2, 0);
    if (nl) { STAGE_B(0, 0, a + 2); STAGE_B(0, 1, a + 2); STAGE_A(0, 0, a + 2); }
    BAR(); WAIT_LGKM0();
    MFMA32(2);
    if (nl) { asm volatile("s_waitcnt vmcnt(6)" ::: "memory"); }
    else    { asm volatile("s_waitcnt vmcnt(0)" ::: "memory"); }
    BAR();
    // ---- mph3: slabs 0,1 of buf1 (+fb buf1); stage buf0.A-h1 <- kt a+2
    DS_A2(0, 1); DS_B(1);
    if (nl) STAGE_A(0, 1, a + 2);
    asm volatile("s_waitcnt lgkmcnt(8)" ::: "memory");
    BAR(); WAIT_LGKM0();
    MFMA32(0);
    BAR();
    // ---- mph4: slabs 2,3 of buf1; stage buf1.{B,A-h0} <- kt b+2; buf0 ready
    DS_A2(2, 1);
    if (nl) { STAGE_B(1, 0, b + 2); STAGE_B(1, 1, b + 2); STAGE_A(1, 0, b + 2); }
    BAR(); WAIT_LGKM0();
    MFMA32(2);
    if (nl) { asm volatile("s_waitcnt vmcnt(6)" ::: "memory"); }
    BAR();
  }

  // -------- epilogue: out = acc * sx[row]*sw[col] + bias[col]
  float swv[4], bv[4];
  #pragma unroll
  for (int nn = 0; nn < 4; ++nn) {
    size_t gc = col0 + wc * 64 + nn * 16 + (lane & 15);
    swv[nn] = sw[gc];
    bv[nn] = bias[gc];
  }
  #pragma unroll
  for (int q = 0; q < 4; ++q) {
    #pragma unroll
    for (int mm = 0; mm < 2; ++mm) {
      #pragma unroll
      for (int j = 0; j < 4; ++j) {
        size_t gr = row0 + q * 64 + wr * 32 + mm * 16 + ((lane >> 4) << 2) + j;
        float sxr = sx[gr];
        float* orow = out + gr * DOUT + col0 + wc * 64 + (lane & 15);
        #pragma unroll
        for (int nn = 0; nn < 4; ++nn)
          orow[nn * 16] = (float)acc[q][mm][nn][j] * (sxr * swv[nn]) + bv[nn];
      }
    }
  }
#undef STAGE
#undef STAGE_A
#undef STAGE_B
#undef DS_A2
#undef DS_B
#undef MFMA32
#undef BAR
#undef WAIT_LGKM0
}

// ---------------- kernel 4: per-token 8-bit fake quant of output, in place ----
__global__ __launch_bounds__(256) void rowquant_kernel(float* __restrict__ out) {
  __shared__ float red[4];
  const int tid = threadIdx.x;
  const size_t row = blockIdx.x;
  float4* g4 = (float4*)(out + row * DOUT);
  float4 v[4];
  float m = 0.0f;
  #pragma unroll
  for (int k = 0; k < 4; ++k) {
    v[k] = g4[tid + k * 256];
    m = fmaxf(m, fmaxf(fmaxf(fabsf(v[k].x), fabsf(v[k].y)),
                       fmaxf(fabsf(v[k].z), fabsf(v[k].w))));
  }
  float mx = block_absmax(m, red);
  float scale = fmaxf(mx / 127.0f, 1e-8f);
  #pragma unroll
  for (int k = 0; k < 4; ++k) {
    float4 w = v[k];
    w.x = fminf(fmaxf(rintf(w.x / scale), -127.0f), 127.0f) * scale;
    w.y = fminf(fmaxf(rintf(w.y / scale), -127.0f), 127.0f) * scale;
    w.z = fminf(fmaxf(rintf(w.z / scale), -127.0f), 127.0f) * scale;
    w.w = fminf(fmaxf(rintf(w.w / scale), -127.0f), 127.0f) * scale;
    g4[tid + k * 256] = w;
  }
}

extern "C" void kernel_launch(void* const* d_in, const int* in_sizes, int n_in,
                              void* d_out, int out_size, void* d_ws, size_t ws_size,
                              hipStream_t stream) {
  (void)in_sizes; (void)n_in; (void)out_size; (void)ws_size;
  const float* input = (const float*)d_in[0];
  const float* weight = (const float*)d_in[1];
  const float* bias = (const float*)d_in[2];
  float* out = (float*)d_out;
  char* ws = (char*)d_ws;
  char* qx = ws;
  char* qw = ws + ((size_t)32 << 20);
  float* sx = (float*)(ws + ((size_t)48 << 20));
  float* sw = (float*)(ws + ((size_t)48 << 20) + ((size_t)32 << 10));

  fwht_quant_kernel<<<NROWS, 256, 0, stream>>>(input, qx, sx);
  wquant_kernel<<<DOUT, 256, 0, stream>>>(weight, qw, sw);
  gemm_kernel<<<512, 512, 0, stream>>>(qx, qw, sx, sw, bias, out);
  rowquant_kernel<<<NROWS, 256, 0, stream>>>(out);
}